// Round 4
// baseline (218.754 us; speedup 1.0000x reference)
//
#include <hip/hip_runtime.h>
#include <hip/hip_bf16.h>

// MetaConv2d fused hypernetwork + dynamic conv, bf16 MFMA. Round 4.
// out[bn,t,o] = sum_{c,k} x[bn,t+k,c] * w[bn,o,c,k] + bias[bn,o]
//   w[bn,p]   = meta[bn,:]·w_lin_w[p,:] + w_lin_b[p],  p = o*192 + c*3 + k
//
// Block = 8 nodes, 1024 threads (16 waves = 8 nodes x 2 t-halves), grid 1024.
// 4 phases = 2 c-chunks(32) x 2 o-halves(32). Per phase per wave:
//   hyper: 12 tiles (2 o-rows x 2 cc-halves x 3 k) -> next LDS buffer
//   conv : 6 B ds_reads (issued first), 6 x A-frags reused across 2 o-tiles,
//          12 MFMA. One barrier per phase.
// LDS: dynamic 123 KB (2 x 60.2 KB w-buffers) + 2 KB static bias.
// ws: wlwbf bf16 copy of w_lin_w + wlbR[o][k][c] f32 rearrangement of w_lin_b.

#define BN_TOT   8192
#define C_IN     64
#define C_OUT    64
#define M_DIM    32
#define S_OUT    62

#define NT       8            // nodes per block
#define NTHREADS 1024         // 16 waves
#define OSTR     120          // shorts per o: 96 j (3k x 32cc) + 24 pad; 240B (16B-mult, 2-way banks)
#define NODESTR  3848         // 32*OSTR + 8
#define HALFS    (NT * NODESTR)          // 30784 shorts per buffer
#define DYNB     (2 * HALFS * 2)         // 123136 B dynamic LDS
#define WLW_ROWS 12288
#define WS_NEED  (WLW_ROWS * M_DIM * 2 + WLW_ROWS * 4)   // 786432 + 49152

typedef __attribute__((ext_vector_type(8))) short bf16x8;
typedef __attribute__((ext_vector_type(4))) float f32x4;

static __device__ __forceinline__ short f2bf(float f) {
    return __bfloat16_as_short(__float2bfloat16(f));
}

static __device__ __forceinline__ bf16x8 cvt8(float4 a, float4 b) {
    bf16x8 r;
    r[0] = f2bf(a.x); r[1] = f2bf(a.y); r[2] = f2bf(a.z); r[3] = f2bf(a.w);
    r[4] = f2bf(b.x); r[5] = f2bf(b.y); r[6] = f2bf(b.z); r[7] = f2bf(b.w);
    return r;
}

// ---------------- pre-pass 1: w_lin_w f32 -> bf16 ----------------
extern "C" __global__ void wlw_to_bf16(const float* __restrict__ src,
                                       short* __restrict__ dst) {
    const int i = (blockIdx.x * 256 + threadIdx.x) * 8;   // 192 blocks cover 12288*32
    const float4 a = *reinterpret_cast<const float4*>(src + i);
    const float4 b = *reinterpret_cast<const float4*>(src + i + 4);
    *reinterpret_cast<bf16x8*>(dst + i) = cvt8(a, b);
}

// ---------------- pre-pass 2: wlb -> wlbR[o][k][c] f32 ----------------
extern "C" __global__ void wlb_rearr(const float* __restrict__ wlb,
                                     float* __restrict__ wlbR) {
    const int i = blockIdx.x * 256 + threadIdx.x;         // 48 blocks cover 12288
    const int o = i / 192;
    const int r = i - o * 192;
    const int k = r >> 6;
    const int c = r & 63;
    wlbR[i] = wlb[o * 192 + c * 3 + k];
}

// ---------------- fused kernel ----------------
template <int USE_WS>
__global__ void __launch_bounds__(NTHREADS, 4)
metaconv_fused(const float* __restrict__ meta,   // [8192][32]
               const float* __restrict__ x,      // [8192][64][64]
               const float* __restrict__ wlw,    // [12288][32] f32
               const short* __restrict__ wlwbf,  // [12288][32] bf16 (ws)
               const float* __restrict__ wlb,    // [12288] natural order
               const float* __restrict__ wlbR,   // [64][3][64] rearranged (ws)
               const float* __restrict__ blw,    // [64][32]
               const float* __restrict__ blb,    // [64]
               float* __restrict__ out)          // [8192][62][64]
{
    extern __shared__ __align__(16) short wsh[];          // 2 * HALFS
    __shared__ float bias_s[NT][C_OUT];

    const int tid   = threadIdx.x;
    const int wave  = tid >> 6;                  // 0..15
    const int lane  = tid & 63;
    const int l16   = lane & 15;
    const int g     = lane >> 4;
    const int node  = wave & (NT - 1);
    const int thalf = wave >> 3;
    const int bn0   = blockIdx.x * NT;

    // per-block bias table (tid < 512): bias[node][o] = meta·b_lin_w[o] + b_lin_b[o]
    if (tid < NT * C_OUT) {
        const int bnode = tid >> 6;
        const int o     = tid & 63;
        const float* mrow = meta + (size_t)(bn0 + bnode) * M_DIM;
        const float* brow = blw + o * M_DIM;
        float s = blb[o];
        #pragma unroll
        for (int m = 0; m < M_DIM; ++m) s += mrow[m] * brow[m];
        bias_s[bnode][o] = s;
    }

    // meta B-fragment (cols = nodes; cols 8..15 duplicate, discarded on write)
    bf16x8 metaF;
    {
        const float* mp = meta + (size_t)(bn0 + (l16 & (NT - 1))) * M_DIM + g * 8;
        metaF = cvt8(*reinterpret_cast<const float4*>(mp),
                     *reinterpret_cast<const float4*>(mp + 4));
    }

    const f32x4 ZV = {0.f, 0.f, 0.f, 0.f};
    f32x4 acc[2][4];                             // [t-tile local][o-tile 0..3]
    #pragma unroll
    for (int t = 0; t < 2; ++t)
        #pragma unroll
        for (int o = 0; o < 4; ++o) acc[t][o] = ZV;

    // hyper phase: 12 tiles/wave = 2 o-rows x 2 cc-halves x 3 k.
    // D lane(l16,g): col=node=l16 (valid l16<NT), rows cc_local = ch*16 + g*4 + r.
    auto hyper_phase = [&](int c0, int oh, int buf) {
        #pragma unroll
        for (int ou = 0; ou < 2; ++ou) {
            const int o_l = wave * 2 + ou;       // o within half, 0..31
            const int og  = oh * 32 + o_l;       // global o
            #pragma unroll
            for (int ch = 0; ch < 2; ++ch) {
                #pragma unroll
                for (int k = 0; k < 3; ++k) {
                    const int p = og * 192 + (c0 + ch * 16 + l16) * 3 + k;
                    bf16x8 aF;
                    f32x4 Cf;
                    if constexpr (USE_WS) {
                        aF = *reinterpret_cast<const bf16x8*>(wlwbf + (size_t)p * M_DIM + g * 8);
                        const float4 cf = *reinterpret_cast<const float4*>(
                            wlbR + (og * 3 + k) * 64 + c0 + ch * 16 + g * 4);
                        Cf[0] = cf.x; Cf[1] = cf.y; Cf[2] = cf.z; Cf[3] = cf.w;
                    } else {
                        const float* wp = wlw + (size_t)p * M_DIM + g * 8;
                        aF = cvt8(*reinterpret_cast<const float4*>(wp),
                                  *reinterpret_cast<const float4*>(wp + 4));
                        const int cb = c0 + ch * 16 + g * 4;
                        const int pb = og * 192 + k;
                        Cf[0] = wlb[pb + (cb + 0) * 3];
                        Cf[1] = wlb[pb + (cb + 1) * 3];
                        Cf[2] = wlb[pb + (cb + 2) * 3];
                        Cf[3] = wlb[pb + (cb + 3) * 3];
                    }
                    const f32x4 d = __builtin_amdgcn_mfma_f32_16x16x32_bf16(aF, metaF, Cf, 0, 0, 0);
                    if (l16 < NT) {
                        const int off = buf + l16 * NODESTR + o_l * OSTR + k * 32 + ch * 16 + g * 4;
                        *reinterpret_cast<short4*>(&wsh[off]) =
                            make_short4(f2bf(d[0]), f2bf(d[1]), f2bf(d[2]), f2bf(d[3]));
                    }
                }
            }
        }
    };

    const float* xb = x + (size_t)(bn0 + node) * (64 * C_IN);

    // prologue: fill buffer 0 with phase 0 (c0=0, oh=0)
    hyper_phase(0, 0, 0);
    __syncthreads();

    #pragma unroll
    for (int p = 0; p < 4; ++p) {
        const int c0  = (p >> 1) * 32;
        const int oh  = p & 1;
        const int cur = (p & 1) * HALFS;
        const int nxt = ((p + 1) & 1) * HALFS;

        // conv B-frags first (ready since last barrier; overlap with hyper below)
        const short* wn = &wsh[cur + node * NODESTR];
        bf16x8 B[2][3];
        #pragma unroll
        for (int ol = 0; ol < 2; ++ol)
            #pragma unroll
            for (int k = 0; k < 3; ++k)
                B[ol][k] = *reinterpret_cast<const bf16x8*>(
                    wn + (ol * 16 + l16) * OSTR + k * 32 + g * 8);

        // hyper for next phase into the other buffer
        if (p < 3) hyper_phase(((p + 1) >> 1) * 32, (p + 1) & 1, nxt);

        // conv: 6 A-frags (t-tile x k), each reused across 2 o-tiles
        #pragma unroll
        for (int ttl = 0; ttl < 2; ++ttl) {
            #pragma unroll
            for (int k = 0; k < 3; ++k) {
                int row = thalf * 32 + ttl * 16 + l16 + k;
                row = row < 63 ? row : 63;               // rows t>=62 discarded
                const float* xp = xb + row * C_IN + c0 + g * 8;
                const bf16x8 A = cvt8(*reinterpret_cast<const float4*>(xp),
                                      *reinterpret_cast<const float4*>(xp + 4));
                #pragma unroll
                for (int ol = 0; ol < 2; ++ol)
                    acc[ttl][oh * 2 + ol] = __builtin_amdgcn_mfma_f32_16x16x32_bf16(
                        A, B[ol][k], acc[ttl][oh * 2 + ol], 0, 0, 0);
            }
        }
        __syncthreads();
    }

    // ---------------- epilogue: add bias, store f32 ----------------
    float* ob = out + (size_t)(bn0 + node) * (S_OUT * C_OUT);
    #pragma unroll
    for (int ttl = 0; ttl < 2; ++ttl) {
        #pragma unroll
        for (int ot = 0; ot < 4; ++ot) {
            const int o  = ot * 16 + l16;
            const float bv = bias_s[node][o];
            #pragma unroll
            for (int r = 0; r < 4; ++r) {
                const int t = thalf * 32 + ttl * 16 + g * 4 + r;
                if (t < S_OUT) ob[t * C_OUT + o] = acc[ttl][ot][r] + bv;
            }
        }
    }
}

extern "C" void kernel_launch(void* const* d_in, const int* in_sizes, int n_in,
                              void* d_out, int out_size, void* d_ws, size_t ws_size,
                              hipStream_t stream) {
    const float* meta = (const float*)d_in[0];
    const float* x    = (const float*)d_in[1];
    const float* wlw  = (const float*)d_in[2];
    const float* wlb  = (const float*)d_in[3];
    const float* blw  = (const float*)d_in[4];
    const float* blb  = (const float*)d_in[5];
    float* out = (float*)d_out;
    (void)in_sizes; (void)n_in; (void)out_size;

    short* wlwbf = (short*)d_ws;
    float* wlbR  = (float*)((char*)d_ws + (size_t)WLW_ROWS * M_DIM * 2);

    if (ws_size >= (size_t)WS_NEED) {
        (void)hipFuncSetAttribute((const void*)&metaconv_fused<1>,
                                  hipFuncAttributeMaxDynamicSharedMemorySize, DYNB);
        wlw_to_bf16<<<dim3(WLW_ROWS * M_DIM / (256 * 8)), dim3(256), 0, stream>>>(wlw, wlwbf);
        wlb_rearr<<<dim3(WLW_ROWS / 256), dim3(256), 0, stream>>>(wlb, wlbR);
        metaconv_fused<1><<<dim3(BN_TOT / NT), dim3(NTHREADS), DYNB, stream>>>(
            meta, x, wlw, wlwbf, wlb, wlbR, blw, blb, out);
    } else {
        (void)hipFuncSetAttribute((const void*)&metaconv_fused<0>,
                                  hipFuncAttributeMaxDynamicSharedMemorySize, DYNB);
        metaconv_fused<0><<<dim3(BN_TOT / NT), dim3(NTHREADS), DYNB, stream>>>(
            meta, x, wlw, wlwbf, wlb, wlbR, blw, blb, out);
    }
}